// Round 17
// baseline (123.673 us; speedup 1.0000x reference)
//
#include <hip/hip_runtime.h>
#include <math.h>

#define ATOM 64

typedef float f32x4 __attribute__((ext_vector_type(4)));

// ===========================================================================
// D[k][q] = sum_l B[l][k]*B[l][q];  B[l][q] = Rsum[l]*be2[q] + sum_e Bh[l][e]*We2[e][q]
// e2 column layout: e2[q] = { be2[q], We2[0..9][q], pad }
// ===========================================================================
__device__ __forceinline__ void make_D(const float (&Bh)[4][10], const float (&Rsum)[4],
                                       const float (*e2)[12], float (&D)[20])
{
    float Bk[2][4];
#pragma unroll
    for (int k=0;k<2;++k) {
        const float4 c0 = *(const float4*)&e2[k][0];
        const float4 c1 = *(const float4*)&e2[k][4];
        const float4 c2 = *(const float4*)&e2[k][8];
#pragma unroll
        for (int l=0;l<4;++l) {
            Bk[k][l] = Rsum[l]*c0.x + Bh[l][0]*c0.y + Bh[l][1]*c0.z + Bh[l][2]*c0.w
                     + Bh[l][3]*c1.x + Bh[l][4]*c1.y + Bh[l][5]*c1.z + Bh[l][6]*c1.w
                     + Bh[l][7]*c2.x + Bh[l][8]*c2.y + Bh[l][9]*c2.z;
        }
    }
#pragma unroll
    for (int q=0;q<10;++q) {
        const float4 c0 = *(const float4*)&e2[q][0];
        const float4 c1 = *(const float4*)&e2[q][4];
        const float4 c2 = *(const float4*)&e2[q][8];
        float Bq[4];
#pragma unroll
        for (int l=0;l<4;++l) {
            Bq[l] = Rsum[l]*c0.x + Bh[l][0]*c0.y + Bh[l][1]*c0.z + Bh[l][2]*c0.w
                  + Bh[l][3]*c1.x + Bh[l][4]*c1.y + Bh[l][5]*c1.z + Bh[l][6]*c1.w
                  + Bh[l][7]*c2.x + Bh[l][8]*c2.y + Bh[l][9]*c2.z;
        }
        D[q]    = Bk[0][0]*Bq[0]+Bk[0][1]*Bq[1]+Bk[0][2]*Bq[2]+Bk[0][3]*Bq[3];
        D[10+q] = Bk[1][0]*Bq[0]+Bk[1][1]*Bq[1]+Bk[1][2]*Bq[2]+Bk[1][3]*Bq[3];
    }
}

// quad-cooperative MLP head (lane jq in 0..3 of a 4-lane subgroup)
__device__ __forceinline__ float mlp_head_quad(const float* __restrict__ x,
                                          const float* __restrict__ w1, const float* __restrict__ b1,
                                          const float* __restrict__ w2, const float* __restrict__ b2,
                                          const float* __restrict__ w3, int jq)
{
    float h1[8];
    {
        float4 ba = *(const float4*)(b1 + 8*jq);
        float4 bb = *(const float4*)(b1 + 8*jq + 4);
        h1[0]=ba.x; h1[1]=ba.y; h1[2]=ba.z; h1[3]=ba.w;
        h1[4]=bb.x; h1[5]=bb.y; h1[6]=bb.z; h1[7]=bb.w;
    }
#pragma unroll
    for (int d=0; d<20; ++d) {
        float4 w0 = *(const float4*)(w1 + d*32 + 8*jq);
        float4 w4 = *(const float4*)(w1 + d*32 + 8*jq + 4);
        float xv = x[d];
        h1[0] += xv*w0.x; h1[1] += xv*w0.y; h1[2] += xv*w0.z; h1[3] += xv*w0.w;
        h1[4] += xv*w4.x; h1[5] += xv*w4.y; h1[6] += xv*w4.z; h1[7] += xv*w4.w;
    }
#pragma unroll
    for (int o=0;o<8;++o) h1[o] = fmaxf(h1[o], 0.f);

    float s = 0.f;
#pragma unroll
    for (int half=0; half<2; ++half) {
        float p[16];
#pragma unroll
        for (int q=0;q<16;++q) p[q] = 0.f;
#pragma unroll
        for (int o=0;o<8;++o) {
            const float* row = w2 + (8*jq + o)*32 + 16*half;
            float hv = h1[o];
#pragma unroll
            for (int q=0;q<4;++q) {
                float4 w = *(const float4*)(row + 4*q);
                p[4*q+0] += hv*w.x; p[4*q+1] += hv*w.y;
                p[4*q+2] += hv*w.z; p[4*q+3] += hv*w.w;
            }
        }
#pragma unroll
        for (int q=0;q<16;++q) { p[q] += __shfl_xor(p[q],1); p[q] += __shfl_xor(p[q],2); }
#pragma unroll
        for (int q=0;q<4;++q) {
            float4 bq = *(const float4*)(b2 + 16*half + 4*q);
            float4 wq = *(const float4*)(w3 + 16*half + 4*q);
            s += fmaxf(p[4*q+0]+bq.x, 0.f)*wq.x;
            s += fmaxf(p[4*q+1]+bq.y, 0.f)*wq.y;
            s += fmaxf(p[4*q+2]+bq.z, 0.f)*wq.z;
            s += fmaxf(p[4*q+3]+bq.w, 0.f)*wq.w;
        }
    }
    return s;
}

// ===========================================================================
// R17: single fused kernel. 8 lanes/action (atoms 8u+j), 32 actions/block.
// nt loads (2.5 TB/s ingest, proven R15/R16). After the 8-lane butterfly
// reduce, lanes 0-3 run the POLICY head and lanes 4-7 the VALUE head in
// parallel (quad-cooperative). No intermediate workspace traffic at all.
// ===========================================================================
__global__ __launch_bounds__(256) void k_all(
    const float* __restrict__ Smat, const float* __restrict__ Rraw, const float* __restrict__ Mspec,
    const float* __restrict__ We1, const float* __restrict__ be1,
    const float* __restrict__ We2, const float* __restrict__ be2,
    const float* __restrict__ Wf1, const float* __restrict__ bf1,
    const float* __restrict__ Wf2, const float* __restrict__ bf2,
    const float* __restrict__ Wf3, const float* __restrict__ bf3,
    const float* __restrict__ Wv1, const float* __restrict__ bv1,
    const float* __restrict__ Wv2, const float* __restrict__ bv2,
    const float* __restrict__ Wv3, const float* __restrict__ bv3,
    float* __restrict__ logits, float* __restrict__ pmax,
    float* __restrict__ psum, float* __restrict__ pval, int n)
{
    __shared__ __align__(16) float s_e2[10][12];
    __shared__ __align__(16) float s_f1[640], s_v1[640];
    __shared__ __align__(16) float s_f2[1024], s_v2[1024];
    __shared__ __align__(16) float s_b1[32], s_b2[32], s_f3[32];
    __shared__ __align__(16) float s_bv1[32], s_bv2[32], s_v3[32];
    __shared__ float red_l[32], red_v[32];

    const int tid = threadIdx.x;
    for (int i=tid;i<640;i+=256){ s_f1[i]=Wf1[i]; s_v1[i]=Wv1[i]; }
    for (int i=tid;i<1024;i+=256){ s_f2[i]=Wf2[i]; s_v2[i]=Wv2[i]; }
    if (tid<32){ s_b1[tid]=bf1[tid]; s_b2[tid]=bf2[tid]; s_f3[tid]=Wf3[tid];
                 s_bv1[tid]=bv1[tid]; s_bv2[tid]=bv2[tid]; s_v3[tid]=Wv3[tid]; }
    if (tid<10){
        s_e2[tid][0] = be2[tid];
        for (int e=0;e<10;++e) s_e2[tid][1+e] = We2[e*10+tid];
        s_e2[tid][11] = 0.f;
    }
    __syncthreads();

    const int j   = tid & 7;              // lane within 8-lane action group
    const int grp = tid >> 3;             // action within block (0..31)
    const int act = blockIdx.x*32 + grp;
    const bool active = act < n;
    const int actc = active ? act : (n-1);

    // e1 weights: uniform loads -> scalar regs
    float e1w0[10], e1w1[10], e1w2[10], e1w3[10];
#pragma unroll
    for (int e=0;e<10;++e){
        e1w0[e]=be1[e]; e1w1[e]=We1[e]; e1w2[e]=We1[10+e]; e1w3[e]=We1[20+e];
    }

    const f32x4* rp = (const f32x4*)Rraw + (size_t)actc*ATOM + j;
    const float* sp = Smat  + (size_t)actc*ATOM + j;
    const float* mp = Mspec + (size_t)actc*(ATOM*3) + 3*j;

    float Bh[4][10];
    float Rsum[4] = {0.f,0.f,0.f,0.f};
#pragma unroll
    for (int l=0;l<4;++l)
#pragma unroll
        for (int e=0;e<10;++e) Bh[l][e]=0.f;

    float a0h[10], a0r[4];
#pragma unroll
    for (int e=0;e<10;++e) a0h[e]=0.f;
    a0r[0]=a0r[1]=a0r[2]=a0r[3]=0.f;

    // ---- 2-deep software pipeline over 8 atom-steps, nt loads ----
    f32x4 rA,rB;
    float sA,sB;
    float mA0,mA1,mA2, mB0,mB1,mB2;

#define LOADST(R_,S_,M0_,M1_,M2_,u) \
    { R_ = __builtin_nontemporal_load(rp + 8*(u)); \
      S_ = __builtin_nontemporal_load(sp + 8*(u)); \
      M0_ = __builtin_nontemporal_load(mp + 24*(u)); \
      M1_ = __builtin_nontemporal_load(mp + 24*(u)+1); \
      M2_ = __builtin_nontemporal_load(mp + 24*(u)+2); }

#define STEPST(R_,S_,M0_,M1_,M2_,FIRST) \
    { const float s_ = S_; \
      const float Rl0=s_*R_.x, Rl1=s_*R_.y, Rl2=s_*R_.z, Rl3=s_*R_.w; \
      const float sg0=s_*M0_, sg1=s_*M1_, sg2=s_*M2_; \
      float h[10]; \
      _Pragma("unroll") \
      for (int e=0;e<10;++e) \
          h[e] = fmaxf(0.f, e1w0[e] + sg0*e1w1[e] + sg1*e1w2[e] + sg2*e1w3[e]); \
      Rsum[0]+=Rl0; Rsum[1]+=Rl1; Rsum[2]+=Rl2; Rsum[3]+=Rl3; \
      _Pragma("unroll") \
      for (int e=0;e<10;++e){ \
          const float he=h[e]; \
          Bh[0][e]+=Rl0*he; Bh[1][e]+=Rl1*he; Bh[2][e]+=Rl2*he; Bh[3][e]+=Rl3*he; } \
      if (FIRST && j==0){ \
          _Pragma("unroll") \
          for (int e=0;e<10;++e) a0h[e]=h[e]; \
          a0r[0]=Rl0; a0r[1]=Rl1; a0r[2]=Rl2; a0r[3]=Rl3; } }

    LOADST(rA,sA,mA0,mA1,mA2, 0)
    LOADST(rB,sB,mB0,mB1,mB2, 1)

    STEPST(rA,sA,mA0,mA1,mA2, true)   LOADST(rA,sA,mA0,mA1,mA2, 2)
    STEPST(rB,sB,mB0,mB1,mB2, false)  LOADST(rB,sB,mB0,mB1,mB2, 3)
    STEPST(rA,sA,mA0,mA1,mA2, false)  LOADST(rA,sA,mA0,mA1,mA2, 4)
    STEPST(rB,sB,mB0,mB1,mB2, false)  LOADST(rB,sB,mB0,mB1,mB2, 5)
    STEPST(rA,sA,mA0,mA1,mA2, false)  LOADST(rA,sA,mA0,mA1,mA2, 6)
    STEPST(rB,sB,mB0,mB1,mB2, false)  LOADST(rB,sB,mB0,mB1,mB2, 7)
    STEPST(rA,sA,mA0,mA1,mA2, false)
    STEPST(rB,sB,mB0,mB1,mB2, false)

#undef LOADST
#undef STEPST

    // 8-lane butterfly-reduce the 44 accumulators (xor 1,2,4)
#pragma unroll
    for (int l=0;l<4;++l) {
        float v=Rsum[l];
        v+=__shfl_xor(v,1); v+=__shfl_xor(v,2); v+=__shfl_xor(v,4);
        Rsum[l]=v;
#pragma unroll
        for (int e=0;e<10;++e) {
            float w=Bh[l][e];
            w+=__shfl_xor(w,1); w+=__shfl_xor(w,2); w+=__shfl_xor(w,4);
            Bh[l][e]=w;
        }
    }

    // broadcast atom-0 state from the 8-group's base lane
    const int base = (tid & 63) & 56;
    float b0h[10], b0r[4];
#pragma unroll
    for (int e=0;e<10;++e) b0h[e] = __shfl(a0h[e], base);
#pragma unroll
    for (int l=0;l<4;++l)  b0r[l] = __shfl(a0r[l], base);

    // lanes 4-7: value head -> remove atom-0 rank-1 contribution
    const bool isval = (j >= 4);
    if (isval) {
#pragma unroll
        for (int l=0;l<4;++l){
            Rsum[l] -= b0r[l];
#pragma unroll
            for (int e=0;e<10;++e) Bh[l][e] -= b0r[l]*b0h[e];
        }
    }

    float D[20];
    make_D(Bh, Rsum, s_e2, D);

    const int jq = j & 3;
    const float* w1 = isval ? s_v1  : s_f1;
    const float* b1 = isval ? s_bv1 : s_b1;
    const float* w2 = isval ? s_v2  : s_f2;
    const float* b2 = isval ? s_bv2 : s_b2;
    const float* w3 = isval ? s_v3  : s_f3;
    const float  b3 = isval ? bv3[0] : bf3[0];
    const float  outv = mlp_head_quad(D, w1, b1, w2, b2, w3, jq) + b3;

    if (j==0) {
        red_l[grp] = active ? outv : -INFINITY;
        if (active) logits[act] = outv;
    } else if (j==4) {
        red_v[grp] = active ? outv : 0.f;
    }
    __syncthreads();

    if (tid < 32) {
        float m = red_l[tid];
#pragma unroll
        for (int k=1;k<32;k<<=1) m = fmaxf(m, __shfl_xor(m,k));
        float ssum = expf(red_l[tid] - m);     // -inf -> 0
        float vsum = red_v[tid];
#pragma unroll
        for (int k=1;k<32;k<<=1){ ssum += __shfl_xor(ssum,k); vsum += __shfl_xor(vsum,k); }
        if (tid==0){ pmax[blockIdx.x]=m; psum[blockIdx.x]=ssum; pval[blockIdx.x]=vsum; }
    }
}

// ===========================================================================
// Merge per-block partials -> logZ, value ; apply shift
// ===========================================================================
__global__ __launch_bounds__(256) void k_reduce(const float* __restrict__ pmax,
                                                const float* __restrict__ psum,
                                                const float* __restrict__ pval,
                                                int nb,
                                                float* __restrict__ logZ,
                                                float* __restrict__ value_out)
{
    __shared__ float sm[256];
    const int tid = threadIdx.x;
    float m = -INFINITY;
    for (int i=tid;i<nb;i+=256) m = fmaxf(m, pmax[i]);
    sm[tid]=m; __syncthreads();
    for (int s=128;s>0;s>>=1){ if (tid<s) sm[tid]=fmaxf(sm[tid],sm[tid+s]); __syncthreads(); }
    const float M = sm[0]; __syncthreads();

    float ssum=0.f, vsum=0.f;
    for (int i=tid;i<nb;i+=256){ ssum += psum[i]*expf(pmax[i]-M); vsum += pval[i]; }
    sm[tid]=ssum; __syncthreads();
    for (int s=128;s>0;s>>=1){ if (tid<s) sm[tid]+=sm[tid+s]; __syncthreads(); }
    const float S = sm[0]; __syncthreads();

    sm[tid]=vsum; __syncthreads();
    for (int s=128;s>0;s>>=1){ if (tid<s) sm[tid]+=sm[tid+s]; __syncthreads(); }
    if (tid==0){ *logZ = M + logf(S); *value_out = sm[0]; }
}

__global__ __launch_bounds__(256) void k_apply(const float* __restrict__ logits,
                                               const float* __restrict__ logZ,
                                               float* __restrict__ out, int n)
{
    const int i = blockIdx.x*256 + threadIdx.x;
    if (i < n) out[i] = logits[i] - logZ[0];
}

extern "C" void kernel_launch(void* const* d_in, const int* in_sizes, int n_in,
                              void* d_out, int out_size, void* d_ws, size_t ws_size,
                              hipStream_t stream)
{
    const float* Smat  = (const float*)d_in[0];
    const float* Rraw  = (const float*)d_in[1];
    const float* Mspec = (const float*)d_in[2];
    const float* We1 = (const float*)d_in[3];  const float* be1 = (const float*)d_in[4];
    const float* We2 = (const float*)d_in[5];  const float* be2 = (const float*)d_in[6];
    const float* Wf1 = (const float*)d_in[7];  const float* bf1 = (const float*)d_in[8];
    const float* Wf2 = (const float*)d_in[9];  const float* bf2 = (const float*)d_in[10];
    const float* Wf3 = (const float*)d_in[11]; const float* bf3 = (const float*)d_in[12];
    const float* Wv1 = (const float*)d_in[13]; const float* bv1 = (const float*)d_in[14];
    const float* Wv2 = (const float*)d_in[15]; const float* bv2 = (const float*)d_in[16];
    const float* Wv3 = (const float*)d_in[17]; const float* bv3 = (const float*)d_in[18];

    const int n  = in_sizes[0] / ATOM;
    const int nb = (n + 31) / 32;             // k_all blocks (32 actions each)

    float* ws     = (float*)d_ws;
    float* logits = ws;                       // [n]
    float* pmax   = ws + n;                   // [nb]
    float* psum   = pmax + nb;                // [nb]
    float* pval   = psum + nb;                // [nb]
    float* logZ   = pval + nb;                // [1]
    float* out    = (float*)d_out;            // [n] policy, [1] value

    k_all<<<nb, 256, 0, stream>>>(Smat, Rraw, Mspec,
                                  We1, be1, We2, be2,
                                  Wf1, bf1, Wf2, bf2, Wf3, bf3,
                                  Wv1, bv1, Wv2, bv2, Wv3, bv3,
                                  logits, pmax, psum, pval, n);
    k_reduce<<<1, 256, 0, stream>>>(pmax, psum, pval, nb, logZ, out + n);
    k_apply<<<(n + 255)/256, 256, 0, stream>>>(logits, logZ, out, n);
}

// Round 18
// 90.743 us; speedup vs baseline: 1.3629x; 1.3629x over previous
//
#include <hip/hip_runtime.h>
#include <math.h>

#define ATOM 64

typedef float f32x4 __attribute__((ext_vector_type(4)));

// ===========================================================================
// D[k][q] = sum_l B[l][k]*B[l][q];  B[l][q] = Rsum[l]*be2[q] + sum_e Bh[l][e]*We2[e][q]
// e2 column layout: e2[q] = { be2[q], We2[0..9][q], pad } — reads are wave-uniform (broadcast)
// ===========================================================================
__device__ __forceinline__ void make_D(const float (&Bh)[4][10], const float (&Rsum)[4],
                                       const float (*e2)[12], float (&D)[20])
{
    float Bk[2][4];
#pragma unroll
    for (int k=0;k<2;++k) {
        const float4 c0 = *(const float4*)&e2[k][0];
        const float4 c1 = *(const float4*)&e2[k][4];
        const float4 c2 = *(const float4*)&e2[k][8];
#pragma unroll
        for (int l=0;l<4;++l) {
            Bk[k][l] = Rsum[l]*c0.x + Bh[l][0]*c0.y + Bh[l][1]*c0.z + Bh[l][2]*c0.w
                     + Bh[l][3]*c1.x + Bh[l][4]*c1.y + Bh[l][5]*c1.z + Bh[l][6]*c1.w
                     + Bh[l][7]*c2.x + Bh[l][8]*c2.y + Bh[l][9]*c2.z;
        }
    }
#pragma unroll
    for (int q=0;q<10;++q) {
        const float4 c0 = *(const float4*)&e2[q][0];
        const float4 c1 = *(const float4*)&e2[q][4];
        const float4 c2 = *(const float4*)&e2[q][8];
        float Bq[4];
#pragma unroll
        for (int l=0;l<4;++l) {
            Bq[l] = Rsum[l]*c0.x + Bh[l][0]*c0.y + Bh[l][1]*c0.z + Bh[l][2]*c0.w
                  + Bh[l][3]*c1.x + Bh[l][4]*c1.y + Bh[l][5]*c1.z + Bh[l][6]*c1.w
                  + Bh[l][7]*c2.x + Bh[l][8]*c2.y + Bh[l][9]*c2.z;
        }
        D[q]    = Bk[0][0]*Bq[0]+Bk[0][1]*Bq[1]+Bk[0][2]*Bq[2]+Bk[0][3]*Bq[3];
        D[10+q] = Bk[1][0]*Bq[0]+Bk[1][1]*Bq[1]+Bk[1][2]*Bq[2]+Bk[1][3]*Bq[3];
    }
}

// quad-cooperative MLP head (lane jq in 0..3). Weight pointers are
// wave-uniform (head is wave-uniform after the remap) -> SGPR-based reads.
__device__ __forceinline__ float mlp_head_quad(const float* __restrict__ x,
                                          const float* __restrict__ w1, const float* __restrict__ b1,
                                          const float* __restrict__ w2, const float* __restrict__ b2,
                                          const float* __restrict__ w3, int jq)
{
    float h1[8];
    {
        float4 ba = *(const float4*)(b1 + 8*jq);
        float4 bb = *(const float4*)(b1 + 8*jq + 4);
        h1[0]=ba.x; h1[1]=ba.y; h1[2]=ba.z; h1[3]=ba.w;
        h1[4]=bb.x; h1[5]=bb.y; h1[6]=bb.z; h1[7]=bb.w;
    }
#pragma unroll
    for (int d=0; d<20; ++d) {
        float4 w0 = *(const float4*)(w1 + d*32 + 8*jq);
        float4 w4 = *(const float4*)(w1 + d*32 + 8*jq + 4);
        float xv = x[d];
        h1[0] += xv*w0.x; h1[1] += xv*w0.y; h1[2] += xv*w0.z; h1[3] += xv*w0.w;
        h1[4] += xv*w4.x; h1[5] += xv*w4.y; h1[6] += xv*w4.z; h1[7] += xv*w4.w;
    }
#pragma unroll
    for (int o=0;o<8;++o) h1[o] = fmaxf(h1[o], 0.f);

    float s = 0.f;
#pragma unroll
    for (int half=0; half<2; ++half) {
        float p[16];
#pragma unroll
        for (int q=0;q<16;++q) p[q] = 0.f;
#pragma unroll
        for (int o=0;o<8;++o) {
            const float* row = w2 + (8*jq + o)*32 + 16*half;
            float hv = h1[o];
#pragma unroll
            for (int q=0;q<4;++q) {
                float4 w = *(const float4*)(row + 4*q);
                p[4*q+0] += hv*w.x; p[4*q+1] += hv*w.y;
                p[4*q+2] += hv*w.z; p[4*q+3] += hv*w.w;
            }
        }
#pragma unroll
        for (int q=0;q<16;++q) { p[q] += __shfl_xor(p[q],1); p[q] += __shfl_xor(p[q],2); }
#pragma unroll
        for (int q=0;q<4;++q) {
            float4 bq = *(const float4*)(b2 + 16*half + 4*q);
            float4 wq = *(const float4*)(w3 + 16*half + 4*q);
            s += fmaxf(p[4*q+0]+bq.x, 0.f)*wq.x;
            s += fmaxf(p[4*q+1]+bq.y, 0.f)*wq.y;
            s += fmaxf(p[4*q+2]+bq.z, 0.f)*wq.z;
            s += fmaxf(p[4*q+3]+bq.w, 0.f)*wq.w;
        }
    }
    return s;
}

// ===========================================================================
// R18: single fused kernel. Phase 1 = R16 k_embed (nt loads, 2.5 TB/s).
// Phase 2 = per-action state -> LDS (stride 59, conflict-free).
// Phase 3 = remap: 64 quads = 32 actions x 2 heads; head wave-uniform
// (p>>5) so weight reads are broadcast / benign 4-way (R3-proven pattern).
// ===========================================================================
__global__ __launch_bounds__(256) void k_all(
    const float* __restrict__ Smat, const float* __restrict__ Rraw, const float* __restrict__ Mspec,
    const float* __restrict__ We1, const float* __restrict__ be1,
    const float* __restrict__ We2, const float* __restrict__ be2,
    const float* __restrict__ Wf1, const float* __restrict__ bf1,
    const float* __restrict__ Wf2, const float* __restrict__ bf2,
    const float* __restrict__ Wf3, const float* __restrict__ bf3,
    const float* __restrict__ Wv1, const float* __restrict__ bv1,
    const float* __restrict__ Wv2, const float* __restrict__ bv2,
    const float* __restrict__ Wv3, const float* __restrict__ bv3,
    float* __restrict__ logits, float* __restrict__ pmax,
    float* __restrict__ psum, float* __restrict__ pval, int n)
{
    __shared__ __align__(16) float s_e2[10][12];
    __shared__ __align__(16) float s_f1[640], s_v1[640];
    __shared__ __align__(16) float s_f2[1024], s_v2[1024];
    __shared__ __align__(16) float s_b1[32], s_b2[32], s_f3[32];
    __shared__ __align__(16) float s_bv1[32], s_bv2[32], s_v3[32];
    __shared__ float s_x[32][59];         // per-action exchange: 44 Bh/Rsum + 14 atom0
    __shared__ float red_l[32], red_v[32];

    const int tid = threadIdx.x;
    for (int i=tid;i<640;i+=256){ s_f1[i]=Wf1[i]; s_v1[i]=Wv1[i]; }
    for (int i=tid;i<1024;i+=256){ s_f2[i]=Wf2[i]; s_v2[i]=Wv2[i]; }
    if (tid<32){ s_b1[tid]=bf1[tid]; s_b2[tid]=bf2[tid]; s_f3[tid]=Wf3[tid];
                 s_bv1[tid]=bv1[tid]; s_bv2[tid]=bv2[tid]; s_v3[tid]=Wv3[tid]; }
    if (tid<10){
        s_e2[tid][0] = be2[tid];
        for (int e=0;e<10;++e) s_e2[tid][1+e] = We2[e*10+tid];
        s_e2[tid][11] = 0.f;
    }
    __syncthreads();

    const int j   = tid & 7;              // lane within 8-lane action group
    const int grp = tid >> 3;             // action within block (0..31)
    const int act = blockIdx.x*32 + grp;
    const bool active = act < n;
    const int actc = active ? act : (n-1);

    // e1 weights: uniform loads -> scalar regs
    float e1w0[10], e1w1[10], e1w2[10], e1w3[10];
#pragma unroll
    for (int e=0;e<10;++e){
        e1w0[e]=be1[e]; e1w1[e]=We1[e]; e1w2[e]=We1[10+e]; e1w3[e]=We1[20+e];
    }

    const f32x4* rp = (const f32x4*)Rraw + (size_t)actc*ATOM + j;
    const float* sp = Smat  + (size_t)actc*ATOM + j;
    const float* mp = Mspec + (size_t)actc*(ATOM*3) + 3*j;

    float Bh[4][10];
    float Rsum[4] = {0.f,0.f,0.f,0.f};
#pragma unroll
    for (int l=0;l<4;++l)
#pragma unroll
        for (int e=0;e<10;++e) Bh[l][e]=0.f;

    float a0h[10], a0r[4];
#pragma unroll
    for (int e=0;e<10;++e) a0h[e]=0.f;
    a0r[0]=a0r[1]=a0r[2]=a0r[3]=0.f;

    // ---- Phase 1: 2-deep software pipeline over 8 atom-steps, nt loads ----
    f32x4 rA,rB;
    float sA,sB;
    float mA0,mA1,mA2, mB0,mB1,mB2;

#define LOADST(R_,S_,M0_,M1_,M2_,u) \
    { R_ = __builtin_nontemporal_load(rp + 8*(u)); \
      S_ = __builtin_nontemporal_load(sp + 8*(u)); \
      M0_ = __builtin_nontemporal_load(mp + 24*(u)); \
      M1_ = __builtin_nontemporal_load(mp + 24*(u)+1); \
      M2_ = __builtin_nontemporal_load(mp + 24*(u)+2); }

#define STEPST(R_,S_,M0_,M1_,M2_,FIRST) \
    { const float s_ = S_; \
      const float Rl0=s_*R_.x, Rl1=s_*R_.y, Rl2=s_*R_.z, Rl3=s_*R_.w; \
      const float sg0=s_*M0_, sg1=s_*M1_, sg2=s_*M2_; \
      float h[10]; \
      _Pragma("unroll") \
      for (int e=0;e<10;++e) \
          h[e] = fmaxf(0.f, e1w0[e] + sg0*e1w1[e] + sg1*e1w2[e] + sg2*e1w3[e]); \
      Rsum[0]+=Rl0; Rsum[1]+=Rl1; Rsum[2]+=Rl2; Rsum[3]+=Rl3; \
      _Pragma("unroll") \
      for (int e=0;e<10;++e){ \
          const float he=h[e]; \
          Bh[0][e]+=Rl0*he; Bh[1][e]+=Rl1*he; Bh[2][e]+=Rl2*he; Bh[3][e]+=Rl3*he; } \
      if (FIRST && j==0){ \
          _Pragma("unroll") \
          for (int e=0;e<10;++e) a0h[e]=h[e]; \
          a0r[0]=Rl0; a0r[1]=Rl1; a0r[2]=Rl2; a0r[3]=Rl3; } }

    LOADST(rA,sA,mA0,mA1,mA2, 0)
    LOADST(rB,sB,mB0,mB1,mB2, 1)

    STEPST(rA,sA,mA0,mA1,mA2, true)   LOADST(rA,sA,mA0,mA1,mA2, 2)
    STEPST(rB,sB,mB0,mB1,mB2, false)  LOADST(rB,sB,mB0,mB1,mB2, 3)
    STEPST(rA,sA,mA0,mA1,mA2, false)  LOADST(rA,sA,mA0,mA1,mA2, 4)
    STEPST(rB,sB,mB0,mB1,mB2, false)  LOADST(rB,sB,mB0,mB1,mB2, 5)
    STEPST(rA,sA,mA0,mA1,mA2, false)  LOADST(rA,sA,mA0,mA1,mA2, 6)
    STEPST(rB,sB,mB0,mB1,mB2, false)  LOADST(rB,sB,mB0,mB1,mB2, 7)
    STEPST(rA,sA,mA0,mA1,mA2, false)
    STEPST(rB,sB,mB0,mB1,mB2, false)

#undef LOADST
#undef STEPST

    // 8-lane butterfly-reduce the 44 accumulators (xor 1,2,4)
#pragma unroll
    for (int l=0;l<4;++l) {
        float v=Rsum[l];
        v+=__shfl_xor(v,1); v+=__shfl_xor(v,2); v+=__shfl_xor(v,4);
        Rsum[l]=v;
#pragma unroll
        for (int e=0;e<10;++e) {
            float w=Bh[l][e];
            w+=__shfl_xor(w,1); w+=__shfl_xor(w,2); w+=__shfl_xor(w,4);
            Bh[l][e]=w;
        }
    }

    // ---- Phase 2: lane 0 of each group writes per-action state to LDS ----
    if (j==0) {
#pragma unroll
        for (int l=0;l<4;++l)
#pragma unroll
            for (int e=0;e<10;++e) s_x[grp][l*10+e] = Bh[l][e];
#pragma unroll
        for (int l=0;l<4;++l) s_x[grp][40+l] = Rsum[l];
#pragma unroll
        for (int e=0;e<10;++e) s_x[grp][44+e] = a0h[e];
#pragma unroll
        for (int l=0;l<4;++l) s_x[grp][54+l] = a0r[l];
    }
    __syncthreads();

    // ---- Phase 3: remap. 64 quads = (action 0..31) x (head 0..1).
    // head = p>>5 is WAVE-UNIFORM -> weight pointers in SGPRs.
    const int p    = tid >> 2;
    const int jq   = tid & 3;
    const int a2   = p & 31;
    const int head = p >> 5;
    const int act2 = blockIdx.x*32 + a2;
    const bool active2 = act2 < n;

    float Bh2[4][10], Rs2[4];
#pragma unroll
    for (int l=0;l<4;++l)
#pragma unroll
        for (int e=0;e<10;++e) Bh2[l][e] = s_x[a2][l*10+e];
#pragma unroll
    for (int l=0;l<4;++l) Rs2[l] = s_x[a2][40+l];

    if (head) {  // value head: remove atom-0 rank-1 contribution
#pragma unroll
        for (int l=0;l<4;++l){
            const float r0 = s_x[a2][54+l];
            Rs2[l] -= r0;
#pragma unroll
            for (int e=0;e<10;++e) Bh2[l][e] -= r0 * s_x[a2][44+e];
        }
    }

    float D[20];
    make_D(Bh2, Rs2, s_e2, D);

    const float* w1 = head ? s_v1  : s_f1;
    const float* b1 = head ? s_bv1 : s_b1;
    const float* w2 = head ? s_v2  : s_f2;
    const float* b2 = head ? s_bv2 : s_b2;
    const float* w3 = head ? s_v3  : s_f3;
    const float  b3 = head ? bv3[0] : bf3[0];
    const float  outv = mlp_head_quad(D, w1, b1, w2, b2, w3, jq) + b3;

    if (jq==0) {
        if (head==0) {
            red_l[a2] = active2 ? outv : -INFINITY;
            if (active2) logits[act2] = outv;
        } else {
            red_v[a2] = active2 ? outv : 0.f;
        }
    }
    __syncthreads();

    if (tid < 32) {
        float m = red_l[tid];
#pragma unroll
        for (int k=1;k<32;k<<=1) m = fmaxf(m, __shfl_xor(m,k));
        float ssum = expf(red_l[tid] - m);     // -inf -> 0
        float vsum = red_v[tid];
#pragma unroll
        for (int k=1;k<32;k<<=1){ ssum += __shfl_xor(ssum,k); vsum += __shfl_xor(vsum,k); }
        if (tid==0){ pmax[blockIdx.x]=m; psum[blockIdx.x]=ssum; pval[blockIdx.x]=vsum; }
    }
}

// ===========================================================================
// Merge per-block partials -> logZ, value ; apply shift
// ===========================================================================
__global__ __launch_bounds__(256) void k_reduce(const float* __restrict__ pmax,
                                                const float* __restrict__ psum,
                                                const float* __restrict__ pval,
                                                int nb,
                                                float* __restrict__ logZ,
                                                float* __restrict__ value_out)
{
    __shared__ float sm[256];
    const int tid = threadIdx.x;
    float m = -INFINITY;
    for (int i=tid;i<nb;i+=256) m = fmaxf(m, pmax[i]);
    sm[tid]=m; __syncthreads();
    for (int s=128;s>0;s>>=1){ if (tid<s) sm[tid]=fmaxf(sm[tid],sm[tid+s]); __syncthreads(); }
    const float M = sm[0]; __syncthreads();

    float ssum=0.f, vsum=0.f;
    for (int i=tid;i<nb;i+=256){ ssum += psum[i]*expf(pmax[i]-M); vsum += pval[i]; }
    sm[tid]=ssum; __syncthreads();
    for (int s=128;s>0;s>>=1){ if (tid<s) sm[tid]+=sm[tid+s]; __syncthreads(); }
    const float S = sm[0]; __syncthreads();

    sm[tid]=vsum; __syncthreads();
    for (int s=128;s>0;s>>=1){ if (tid<s) sm[tid]+=sm[tid+s]; __syncthreads(); }
    if (tid==0){ *logZ = M + logf(S); *value_out = sm[0]; }
}

__global__ __launch_bounds__(256) void k_apply(const float* __restrict__ logits,
                                               const float* __restrict__ logZ,
                                               float* __restrict__ out, int n)
{
    const int i = blockIdx.x*256 + threadIdx.x;
    if (i < n) out[i] = logits[i] - logZ[0];
}

extern "C" void kernel_launch(void* const* d_in, const int* in_sizes, int n_in,
                              void* d_out, int out_size, void* d_ws, size_t ws_size,
                              hipStream_t stream)
{
    const float* Smat  = (const float*)d_in[0];
    const float* Rraw  = (const float*)d_in[1];
    const float* Mspec = (const float*)d_in[2];
    const float* We1 = (const float*)d_in[3];  const float* be1 = (const float*)d_in[4];
    const float* We2 = (const float*)d_in[5];  const float* be2 = (const float*)d_in[6];
    const float* Wf1 = (const float*)d_in[7];  const float* bf1 = (const float*)d_in[8];
    const float* Wf2 = (const float*)d_in[9];  const float* bf2 = (const float*)d_in[10];
    const float* Wf3 = (const float*)d_in[11]; const float* bf3 = (const float*)d_in[12];
    const float* Wv1 = (const float*)d_in[13]; const float* bv1 = (const float*)d_in[14];
    const float* Wv2 = (const float*)d_in[15]; const float* bv2 = (const float*)d_in[16];
    const float* Wv3 = (const float*)d_in[17]; const float* bv3 = (const float*)d_in[18];

    const int n  = in_sizes[0] / ATOM;
    const int nb = (n + 31) / 32;             // k_all blocks (32 actions each)

    float* ws     = (float*)d_ws;
    float* logits = ws;                       // [n]
    float* pmax   = ws + n;                   // [nb]
    float* psum   = pmax + nb;                // [nb]
    float* pval   = psum + nb;                // [nb]
    float* logZ   = pval + nb;                // [1]
    float* out    = (float*)d_out;            // [n] policy, [1] value

    k_all<<<nb, 256, 0, stream>>>(Smat, Rraw, Mspec,
                                  We1, be1, We2, be2,
                                  Wf1, bf1, Wf2, bf2, Wf3, bf3,
                                  Wv1, bv1, Wv2, bv2, Wv3, bv3,
                                  logits, pmax, psum, pval, n);
    k_reduce<<<1, 256, 0, stream>>>(pmax, psum, pval, nb, logZ, out + n);
    k_apply<<<(n + 255)/256, 256, 0, stream>>>(logits, logZ, out, n);
}